// Round 1
// baseline (205.969 us; speedup 1.0000x reference)
//
#include <hip/hip_runtime.h>
#include <hip/hip_bf16.h>
#include <math.h>

#define CHANNEL 128

// order-preserving float<->uint mapping for atomicMax on floats
__device__ __forceinline__ unsigned fmap(float f) {
    unsigned u = __float_as_uint(f);
    return u ^ ((unsigned)((int)u >> 31) | 0x80000000u);
}
__device__ __forceinline__ float funmap(unsigned m) {
    unsigned u = (m & 0x80000000u) ? (m ^ 0x80000000u) : ~m;
    return __uint_as_float(u);
}

// grid = R (50), block = CHANNEL (128)
// P2[j][k] = (1/16) * sum_c W[k][c] * (sum_kk relw[j][kk] * W[kk][c])
// rel_norm[j] = sum_k relw[j][k]^2
__global__ void prep_kernel(const float* __restrict__ relw, const float* __restrict__ W,
                            float* __restrict__ P2, float* __restrict__ rel_norm) {
    __shared__ float rw[CHANNEL];
    __shared__ float kr[CHANNEL];
    __shared__ float red[CHANNEL];
    int j = blockIdx.x;
    int c = threadIdx.x;
    float v = relw[j * CHANNEL + c];
    rw[c] = v;
    red[c] = v * v;
    __syncthreads();
    for (int s = CHANNEL / 2; s > 0; s >>= 1) {
        if (c < s) red[c] += red[c + s];
        __syncthreads();
    }
    if (c == 0) rel_norm[j] = red[0];
    // K_rel[j][c] = sum_k rw[k] * W[k][c]   (W reads coalesced over c)
    float acc = 0.f;
    for (int k = 0; k < CHANNEL; ++k) acc += rw[k] * W[k * CHANNEL + c];
    kr[c] = acc;
    __syncthreads();
    // P2[j][k] = (1/16) sum_c W[k][c] * kr[c]
    float acc2 = 0.f;
    for (int cc = 0; cc < CHANNEL; ++cc) acc2 += W[c * CHANNEL + cc] * kr[cc];
    P2[j * CHANNEL + c] = acc2 * 0.0625f;
}

// 16 lanes per edge: d1 = dot(ent[head], ent[tail]); d2 = dot(ent[head], P2[type-1])
__global__ void pass1_kernel(const float* __restrict__ ent, const float* __restrict__ P2,
                             const int* __restrict__ eidx, const int* __restrict__ etype,
                             float* __restrict__ dot_ht, float* __restrict__ score_r,
                             unsigned* __restrict__ m1, int E) {
    int g = blockIdx.x * blockDim.x + threadIdx.x;
    int e = g >> 4;
    int lane = g & 15;
    if (e >= E) return;
    int h = eidx[e];
    int t = eidx[E + e];
    int r = etype[e] - 1;
    const float4* hp = (const float4*)(ent + (size_t)h * CHANNEL);
    const float4* tp = (const float4*)(ent + (size_t)t * CHANNEL);
    const float4* rp = (const float4*)(P2 + r * CHANNEL);
    float d1 = 0.f, d2 = 0.f;
#pragma unroll
    for (int it = 0; it < 2; ++it) {
        float4 hv = hp[lane + 16 * it];
        float4 tv = tp[lane + 16 * it];
        float4 rv = rp[lane + 16 * it];
        d1 += hv.x * tv.x + hv.y * tv.y + hv.z * tv.z + hv.w * tv.w;
        d2 += hv.x * rv.x + hv.y * rv.y + hv.z * rv.z + hv.w * rv.w;
    }
#pragma unroll
    for (int msk = 8; msk > 0; msk >>= 1) {
        d1 += __shfl_xor(d1, msk);
        d2 += __shfl_xor(d2, msk);
    }
    if (lane == 0) {
        dot_ht[e] = d1;
        score_r[e] = d2;
        atomicMax(m1 + h, fmap(d2));
    }
}

__global__ void pass2_kernel(const float* __restrict__ score_r, const int* __restrict__ eidx,
                             const unsigned* __restrict__ m1, float* __restrict__ s1, int E) {
    int e = blockIdx.x * blockDim.x + threadIdx.x;
    if (e >= E) return;
    int h = eidx[e];
    float e1 = expf(score_r[e] - funmap(m1[h]));
    atomicAdd(s1 + h, e1);
}

__global__ void pass3_kernel(const float* __restrict__ score_r, const float* __restrict__ dot_ht,
                             const int* __restrict__ eidx, const int* __restrict__ etype,
                             const unsigned* __restrict__ m1, const float* __restrict__ s1,
                             const float* __restrict__ rel_norm,
                             float* __restrict__ st, unsigned* __restrict__ m2, int E) {
    int e = blockIdx.x * blockDim.x + threadIdx.x;
    if (e >= E) return;
    int h = eidx[e];
    float e1 = expf(score_r[e] - funmap(m1[h]));
    float rs = e1 / s1[h];
    float v = dot_ht[e] + rs * rs * rel_norm[etype[e] - 1];
    st[e] = v;
    atomicMax(m2 + h, fmap(v));
}

__global__ void pass4_kernel(const float* __restrict__ st, const int* __restrict__ eidx,
                             const unsigned* __restrict__ m2, float* __restrict__ s2, int E) {
    int e = blockIdx.x * blockDim.x + threadIdx.x;
    if (e >= E) return;
    int h = eidx[e];
    float e2 = expf(st[e] - funmap(m2[h]));
    atomicAdd(s2 + h, e2);
}

__global__ void pass5_kernel(const float* __restrict__ st, const int* __restrict__ eidx,
                             const unsigned* __restrict__ m2, const float* __restrict__ s2,
                             float* __restrict__ out, int E) {
    int e = blockIdx.x * blockDim.x + threadIdx.x;
    if (e >= E) return;
    int h = eidx[e];
    out[e] = expf(st[e] - funmap(m2[h])) / s2[h];
}

extern "C" void kernel_launch(void* const* d_in, const int* in_sizes, int n_in,
                              void* d_out, int out_size, void* d_ws, size_t ws_size,
                              hipStream_t stream) {
    const float* ent   = (const float*)d_in[0];
    const float* relw  = (const float*)d_in[2];
    const float* W     = (const float*)d_in[3];
    const int*   eidx  = (const int*)d_in[4];
    const int*   etype = (const int*)d_in[5];
    float* out = (float*)d_out;

    const int E = in_sizes[5];
    const int N = in_sizes[0] / CHANNEL;
    const int R = in_sizes[2] / CHANNEL;

    float* ws = (float*)d_ws;
    float*    dot_ht   = ws;
    float*    score_r  = ws + (size_t)E;
    float*    st       = ws + (size_t)2 * E;
    unsigned* m1       = (unsigned*)(ws + (size_t)3 * E);
    float*    s1       = ws + (size_t)3 * E + N;
    unsigned* m2       = (unsigned*)(ws + (size_t)3 * E + 2 * (size_t)N);
    float*    s2       = ws + (size_t)3 * E + 3 * (size_t)N;
    float*    P2       = ws + (size_t)3 * E + 4 * (size_t)N;
    float*    rel_norm = P2 + (size_t)R * CHANNEL;

    // zero m1, s1, m2, s2 (contiguous region). fmap identity for max is 0.
    hipMemsetAsync(m1, 0, (size_t)4 * N * sizeof(float), stream);

    prep_kernel<<<R, CHANNEL, 0, stream>>>(relw, W, P2, rel_norm);

    int b1 = (E * 16 + 255) / 256;
    pass1_kernel<<<b1, 256, 0, stream>>>(ent, P2, eidx, etype, dot_ht, score_r, m1, E);

    int b = (E + 255) / 256;
    pass2_kernel<<<b, 256, 0, stream>>>(score_r, eidx, m1, s1, E);
    pass3_kernel<<<b, 256, 0, stream>>>(score_r, dot_ht, eidx, etype, m1, s1, rel_norm, st, m2, E);
    pass4_kernel<<<b, 256, 0, stream>>>(st, eidx, m2, s2, E);
    pass5_kernel<<<b, 256, 0, stream>>>(st, eidx, m2, s2, out, E);
}